// Round 6
// baseline (118.126 us; speedup 1.0000x reference)
//
#include <hip/hip_runtime.h>
#include <math.h>

#define B_    2
#define C_    64
#define N_    20000
#define K_    16
#define COUT_ 64
#define TNC   64
#define NBC   ((N_ + TNC - 1) / TNC)   // 313
#define TN    16
#define NB    (N_ / TN)                // 1250 (exact)
#define NEDGE (B_ * N_ * K_)           // 640000
#define PREPB 1024                     // prep grid; 640000/1024 = 625 edges/blk

typedef unsigned int   u32;
typedef unsigned short u16;
typedef unsigned long long u64;
typedef __attribute__((ext_vector_type(8))) short bf16x8;   // 8 bf16 = 4 VGPR
typedef __attribute__((ext_vector_type(4))) float f32x4;

static __device__ __forceinline__ u16 f2bf(float f) {
    union { float f; u32 u; } v; v.f = f;
    u32 r = (v.u + 0x7FFFu + ((v.u >> 16) & 1u)) >> 16;  // RNE
    return (u16)r;
}
static __device__ __forceinline__ float uasf(u32 u) {
    union { u32 u; float f; } v; v.u = u; return v.f;
}
static __device__ __forceinline__ bf16x8 asbf(uint4 v) {
    union { uint4 u; bf16x8 b; } c; c.u = v; return c.b;
}

// ---------------------------------------------------------------------------
// prep: 1024 blocks.
//  (1) ALL blocks: edge prep for a 625-edge slice -> ebuf[g] = (i0|i1<<16, s)
//      (NT store: write-once, read-once-coalesced by fused2). This moves the
//      3.84M random pos-gathers + sqrt/exp OFF fused2's critical path and
//      hides them under prep's own streaming latency.
//  (2) blocks 0..625: transpose+cast x [b][c][n] f32 -> xb [b][n][64] bf16
//      (128 B rows). block 626: pack W into MFMA B-fragments:
//      f = ot*4 + {0,1}: (W1-W2) cols {0..31, 32..63}
//      f = ot*4 + {2,3}:  W2     cols {0..31, 32..63}
//      so feat x W^T = x_i (W1-W2)^T + x_j W2^T (no per-edge subtraction).
// ---------------------------------------------------------------------------
__global__ __launch_bounds__(256)
void prep(const float* __restrict__ x, const float* __restrict__ W,
          const int* __restrict__ ei, const float* __restrict__ pos,
          u16* __restrict__ xb, u16* __restrict__ wfrag,
          u64* __restrict__ ebuf) {
    const int bid = blockIdx.x;
    const int t   = threadIdx.x;

    // ---- (1) edge-prep slice: edges [bid*625, bid*625+625) ----
    {
        const int base = bid * (NEDGE / PREPB);
        #pragma unroll
        for (int k = t; k < NEDGE / PREPB; k += 256) {
            const int g = base + k;
            const int b = g / (N_ * K_);
            int i0 = __builtin_nontemporal_load(&ei[g]);           // neighbor
            int i1 = __builtin_nontemporal_load(&ei[NEDGE + g]);   // center
            const float* pb = pos + (size_t)b * 3 * N_;
            float dx = pb[i0]          - pb[i1];
            float dy = pb[N_ + i0]     - pb[N_ + i1];
            float dz = pb[2 * N_ + i0] - pb[2 * N_ + i1];
            float dis = sqrtf(dx * dx + dy * dy + dz * dz);
            float s = 2.0f / (1.0f + __expf(dis));                 // 2*sig(-d)
            u64 rec = (u64)((u32)i0 | ((u32)i1 << 16)) |
                      ((u64)__float_as_uint(s) << 32);
            __builtin_nontemporal_store(rec, &ebuf[g]);
        }
    }

    if (bid == B_ * NBC) {              // ---- W-fragment packer ----
        const int l  = t & 63;
        const int ot = t >> 6;
        const int o  = ot * 16 + (l & 15);
        const int cb = (l >> 4) << 3;   // 8-ch chunk within a 32-col slice
        #pragma unroll
        for (int h = 0; h < 2; ++h) {   // col half: channels h*32 + cb .. +8
            u32 p1[4], p2[4];
            #pragma unroll
            for (int jj = 0; jj < 4; ++jj) {
                int c0 = h * 32 + cb + 2 * jj, c1 = c0 + 1;
                float w1a = W[o * 128 + c0],      w1b = W[o * 128 + c1];
                float w2a = W[o * 128 + 64 + c0], w2b = W[o * 128 + 64 + c1];
                p1[jj] = (u32)f2bf(w1a - w2a) | ((u32)f2bf(w1b - w2b) << 16);
                p2[jj] = (u32)f2bf(w2a)       | ((u32)f2bf(w2b)       << 16);
            }
            *(uint4*)&wfrag[(size_t)((ot * 4 + h)     * 64 + l) * 8] =
                make_uint4(p1[0], p1[1], p1[2], p1[3]);
            *(uint4*)&wfrag[(size_t)((ot * 4 + 2 + h) * 64 + l) * 8] =
                make_uint4(p2[0], p2[1], p2[2], p2[3]);
        }
        return;
    }
    if (bid > B_ * NBC) return;         // blocks 627..1023: edge prep only

    // ---- (2) x transpose+cast tile ----
    __shared__ float tile[64][68];      // [c][n_local], padded
    const int b  = bid / NBC;
    const int n0 = (bid % NBC) * TNC;
    const float* xbase = x + (size_t)b * C_ * N_;
    #pragma unroll
    for (int r = 0; r < 4; ++r) {
        int flat = r * 256 + t;
        int c = flat >> 4, ng = (flat & 15) * 4;
        int n = n0 + ng;
        float4 v;
        if (n + 3 < N_) {
            v = *(const float4*)&xbase[c * N_ + n];
        } else {
            v.x = (n     < N_) ? xbase[c * N_ + n    ] : 0.0f;
            v.y = (n + 1 < N_) ? xbase[c * N_ + n + 1] : 0.0f;
            v.z = (n + 2 < N_) ? xbase[c * N_ + n + 2] : 0.0f;
            v.w = (n + 3 < N_) ? xbase[c * N_ + n + 3] : 0.0f;
        }
        *(float4*)&tile[c][ng] = v;
    }
    __syncthreads();

    const int n = t >> 2, q = t & 3;    // node row, 16-channel quarter
    if (n0 + n < N_) {
        u32 p[8];
        #pragma unroll
        for (int jj = 0; jj < 8; ++jj) {
            float v0 = tile[q * 16 + 2 * jj][n];
            float v1 = tile[q * 16 + 2 * jj + 1][n];
            p[jj] = (u32)f2bf(v0) | ((u32)f2bf(v1) << 16);
        }
        u16* dst = xb + ((size_t)(b * N_ + n0 + n)) * 64 + q * 16;
        *(uint4*)dst       = make_uint4(p[0], p[1], p[2], p[3]);
        *(uint4*)(dst + 8) = make_uint4(p[4], p[5], p[6], p[7]);
    }
}

// ---------------------------------------------------------------------------
// fused2: round-5 gather-to-fragment core, edge prep REMOVED (reads ebuf
// records coalesced, 1 NT load + 1 LDS store / thread). Block = 16 nodes
// (256 edges), 4 waves; wave w owns nodes {w, 4+w, 8+w, 12+w}. Lane l
// loads 16 B chunks x[i1] lo/hi, x[i0] lo/hi of edge (l&15) straight into
// mfma_16x16x32 A-fragments (row = l&15, k-slice = (l>>4)*8):
//   ac_o = xi_lo*(W1-W2)[0:32] + xi_hi*(W1-W2)[32:64]
//        + xj_lo*W2[0:32]      + xj_hi*W2[32:64]
// Epilogue: relu(D+b)*s, k-max over D rows (reg + shfl 16/32).
// ---------------------------------------------------------------------------
__global__ __launch_bounds__(256)
void fused2(const u64* __restrict__ ebuf,
            const u16* __restrict__ xb, const u16* __restrict__ wfrag,
            const float* __restrict__ bias, float* __restrict__ out) {
    __shared__ uint2 esl[256];          // (i0 | i1<<16, s) per edge
    __shared__ float otile[16][66];     // [n_local][o], padded

    const int bi   = blockIdx.x;
    const int b    = bi / NB;
    const int n0   = (bi % NB) * TN;
    const int t    = threadIdx.x;
    const int lane = t & 63;
    const int w    = t >> 6;
    const int g    = lane >> 4;         // k-slice group 0..3
    const int col  = lane & 15;

    // ---- Phase A': coalesced edge-record fill ----
    {
        u64 rec = __builtin_nontemporal_load(&ebuf[(size_t)b * N_ * K_ +
                                                   n0 * K_ + t]);
        esl[t] = make_uint2((u32)rec, (u32)(rec >> 32));
    }

    // ---- W fragments (16 x 16 B coalesced, L2-hot) + bias ----
    bf16x8 wf[16];
    #pragma unroll
    for (int f = 0; f < 16; ++f)
        wf[f] = *(const bf16x8*)&wfrag[(size_t)(f * 64 + lane) * 8];
    const float bo0 = bias[col], bo1 = bias[16 + col],
                bo2 = bias[32 + col], bo3 = bias[48 + col];
    __syncthreads();

    const uint4* xrow = (const uint4*)(xb + (size_t)b * N_ * 64);

    #pragma unroll
    for (int it = 0; it < 4; ++it) {
        const int nt = it * 4 + w;                       // this wave's node
        uint2 ee = esl[nt * 16 + col];                   // edge (l&15)
        int   i0 = (int)(ee.x & 0xFFFFu);
        int   i1 = (int)(ee.x >> 16);
        const uint4* ri = xrow + ((size_t)i1 << 3);      // 128 B row, 8 uint4
        const uint4* rj = xrow + ((size_t)i0 << 3);
        bf16x8 xi_lo = asbf(ri[g]);                      // ch g*8   .. +8
        bf16x8 xi_hi = asbf(ri[4 + g]);                  // ch 32+g*8.. +8
        bf16x8 xj_lo = asbf(rj[g]);
        bf16x8 xj_hi = asbf(rj[4 + g]);

        f32x4 ac0 = {0,0,0,0}, ac1 = ac0, ac2 = ac0, ac3 = ac0;
        ac0 = __builtin_amdgcn_mfma_f32_16x16x32_bf16(xi_lo, wf[0],  ac0, 0,0,0);
        ac0 = __builtin_amdgcn_mfma_f32_16x16x32_bf16(xi_hi, wf[1],  ac0, 0,0,0);
        ac0 = __builtin_amdgcn_mfma_f32_16x16x32_bf16(xj_lo, wf[2],  ac0, 0,0,0);
        ac0 = __builtin_amdgcn_mfma_f32_16x16x32_bf16(xj_hi, wf[3],  ac0, 0,0,0);
        ac1 = __builtin_amdgcn_mfma_f32_16x16x32_bf16(xi_lo, wf[4],  ac1, 0,0,0);
        ac1 = __builtin_amdgcn_mfma_f32_16x16x32_bf16(xi_hi, wf[5],  ac1, 0,0,0);
        ac1 = __builtin_amdgcn_mfma_f32_16x16x32_bf16(xj_lo, wf[6],  ac1, 0,0,0);
        ac1 = __builtin_amdgcn_mfma_f32_16x16x32_bf16(xj_hi, wf[7],  ac1, 0,0,0);
        ac2 = __builtin_amdgcn_mfma_f32_16x16x32_bf16(xi_lo, wf[8],  ac2, 0,0,0);
        ac2 = __builtin_amdgcn_mfma_f32_16x16x32_bf16(xi_hi, wf[9],  ac2, 0,0,0);
        ac2 = __builtin_amdgcn_mfma_f32_16x16x32_bf16(xj_lo, wf[10], ac2, 0,0,0);
        ac2 = __builtin_amdgcn_mfma_f32_16x16x32_bf16(xj_hi, wf[11], ac2, 0,0,0);
        ac3 = __builtin_amdgcn_mfma_f32_16x16x32_bf16(xi_lo, wf[12], ac3, 0,0,0);
        ac3 = __builtin_amdgcn_mfma_f32_16x16x32_bf16(xi_hi, wf[13], ac3, 0,0,0);
        ac3 = __builtin_amdgcn_mfma_f32_16x16x32_bf16(xj_lo, wf[14], ac3, 0,0,0);
        ac3 = __builtin_amdgcn_mfma_f32_16x16x32_bf16(xj_hi, wf[15], ac3, 0,0,0);

        float m0 = 0.f, m1 = 0.f, m2 = 0.f, m3 = 0.f;    // relu*s >= 0
#define EPI(REG) { \
        float sv = uasf(esl[nt * 16 + g * 4 + REG].y); \
        m0 = fmaxf(m0, fmaxf(ac0[REG] + bo0, 0.f) * sv); \
        m1 = fmaxf(m1, fmaxf(ac1[REG] + bo1, 0.f) * sv); \
        m2 = fmaxf(m2, fmaxf(ac2[REG] + bo2, 0.f) * sv); \
        m3 = fmaxf(m3, fmaxf(ac3[REG] + bo3, 0.f) * sv); }
        EPI(0) EPI(1) EPI(2) EPI(3)
#undef EPI
        m0 = fmaxf(m0, __shfl_xor(m0, 16)); m0 = fmaxf(m0, __shfl_xor(m0, 32));
        m1 = fmaxf(m1, __shfl_xor(m1, 16)); m1 = fmaxf(m1, __shfl_xor(m1, 32));
        m2 = fmaxf(m2, __shfl_xor(m2, 16)); m2 = fmaxf(m2, __shfl_xor(m2, 32));
        m3 = fmaxf(m3, __shfl_xor(m3, 16)); m3 = fmaxf(m3, __shfl_xor(m3, 32));
        if (lane < 16) {
            otile[nt][col]      = m0;
            otile[nt][16 + col] = m1;
            otile[nt][32 + col] = m2;
            otile[nt][48 + col] = m3;
        }
    }
    __syncthreads();

    // ---- coalesced writeback: 64 o x 16 n, nontemporal ----
    #pragma unroll
    for (int r = 0; r < 4; ++r) {
        int flat = r * 256 + t;
        int o = flat >> 4, n2 = flat & 15;
        __builtin_nontemporal_store(otile[n2][o],
            &out[((size_t)b * COUT_ + o) * N_ + n0 + n2]);
    }
}

// ---------------------------------------------------------------------------
extern "C" void kernel_launch(void* const* d_in, const int* in_sizes, int n_in,
                              void* d_out, int out_size, void* d_ws, size_t ws_size,
                              hipStream_t stream) {
    const float* x    = (const float*)d_in[0];   // [B, C, N, 1]
    const int*   ei   = (const int*)  d_in[1];   // [2, B, N, K]
    const float* pos  = (const float*)d_in[2];   // [B, 3, N, 1]
    const float* W    = (const float*)d_in[3];   // [COUT, 2C]
    const float* bias = (const float*)d_in[4];   // [COUT]
    float*       out  = (float*)d_out;           // [B, COUT, N, 1]

    u16* xb    = (u16*)d_ws;                     // B*N*64 bf16 = 5.12 MB
    u16* wfrag = xb + (size_t)B_ * N_ * 64;      // 16 KB (B-frag layout)
    u64* ebuf  = (u64*)(wfrag + 64 * 64 * 2);    // 5.12 MB edge records

    hipLaunchKernelGGL(prep, dim3(PREPB), dim3(256), 0, stream,
                       x, W, ei, pos, xb, wfrag, ebuf);
    hipLaunchKernelGGL(fused2, dim3(B_ * NB), dim3(256), 0, stream,
                       ebuf, xb, wfrag, bias, out);
}

// Round 7
// 108.087 us; speedup vs baseline: 1.0929x; 1.0929x over previous
//
#include <hip/hip_runtime.h>
#include <math.h>

#define B_    2
#define C_    64
#define N_    20000
#define K_    16
#define COUT_ 64
#define TNC   64
#define NBC   ((N_ + TNC - 1) / TNC)   // 313
#define TN    16
#define NB    (N_ / TN)                // 1250 (exact)

typedef unsigned int   u32;
typedef unsigned short u16;
typedef __attribute__((ext_vector_type(8))) short bf16x8;   // 8 bf16 = 4 VGPR
typedef __attribute__((ext_vector_type(4))) float f32x4;

static __device__ __forceinline__ u16 f2bf(float f) {
    union { float f; u32 u; } v; v.f = f;
    u32 r = (v.u + 0x7FFFu + ((v.u >> 16) & 1u)) >> 16;  // RNE
    return (u16)r;
}
static __device__ __forceinline__ float uasf(u32 u) {
    union { u32 u; float f; } v; v.u = u; return v.f;
}
static __device__ __forceinline__ bf16x8 asbf(uint4 v) {
    union { uint4 u; bf16x8 b; } c; c.u = v; return c.b;
}

// ---------------------------------------------------------------------------
// precast (round-5 proven): transpose+cast x -> xb [b][n][64] bf16 (128 B
// rows); last block packs W into MFMA B-fragments:
//   f = ot*4 + {0,1}: (W1-W2) cols {0..31, 32..63}
//   f = ot*4 + {2,3}:  W2     cols {0..31, 32..63}
// so feat x W^T = x_i (W1-W2)^T + x_j W2^T (no per-edge subtraction).
// ---------------------------------------------------------------------------
__global__ __launch_bounds__(256)
void precast(const float* __restrict__ x, const float* __restrict__ W,
             u16* __restrict__ xb, u16* __restrict__ wfrag) {
    const int bi = blockIdx.x;
    const int t  = threadIdx.x;

    if (bi == B_ * NBC) {               // ---- W-fragment packer (1 block) ----
        const int l  = t & 63;
        const int ot = t >> 6;
        const int o  = ot * 16 + (l & 15);
        const int cb = (l >> 4) << 3;   // 8-ch chunk within a 32-col slice
        #pragma unroll
        for (int h = 0; h < 2; ++h) {   // col half: channels h*32 + cb .. +8
            u32 p1[4], p2[4];
            #pragma unroll
            for (int jj = 0; jj < 4; ++jj) {
                int c0 = h * 32 + cb + 2 * jj, c1 = c0 + 1;
                float w1a = W[o * 128 + c0],      w1b = W[o * 128 + c1];
                float w2a = W[o * 128 + 64 + c0], w2b = W[o * 128 + 64 + c1];
                p1[jj] = (u32)f2bf(w1a - w2a) | ((u32)f2bf(w1b - w2b) << 16);
                p2[jj] = (u32)f2bf(w2a)       | ((u32)f2bf(w2b)       << 16);
            }
            *(uint4*)&wfrag[(size_t)((ot * 4 + h)     * 64 + l) * 8] =
                make_uint4(p1[0], p1[1], p1[2], p1[3]);
            *(uint4*)&wfrag[(size_t)((ot * 4 + 2 + h) * 64 + l) * 8] =
                make_uint4(p2[0], p2[1], p2[2], p2[3]);
        }
        return;
    }

    __shared__ float tile[64][68];      // [c][n_local], padded
    const int b  = bi / NBC;
    const int n0 = (bi % NBC) * TNC;
    const float* xbase = x + (size_t)b * C_ * N_;
    #pragma unroll
    for (int r = 0; r < 4; ++r) {
        int flat = r * 256 + t;
        int c = flat >> 4, ng = (flat & 15) * 4;
        int n = n0 + ng;
        float4 v;
        if (n + 3 < N_) {
            v = *(const float4*)&xbase[c * N_ + n];
        } else {
            v.x = (n     < N_) ? xbase[c * N_ + n    ] : 0.0f;
            v.y = (n + 1 < N_) ? xbase[c * N_ + n + 1] : 0.0f;
            v.z = (n + 2 < N_) ? xbase[c * N_ + n + 2] : 0.0f;
            v.w = (n + 3 < N_) ? xbase[c * N_ + n + 3] : 0.0f;
        }
        *(float4*)&tile[c][ng] = v;
    }
    __syncthreads();

    const int n = t >> 2, q = t & 3;    // node row, 16-channel quarter
    if (n0 + n < N_) {
        u32 p[8];
        #pragma unroll
        for (int jj = 0; jj < 8; ++jj) {
            float v0 = tile[q * 16 + 2 * jj][n];
            float v1 = tile[q * 16 + 2 * jj + 1][n];
            p[jj] = (u32)f2bf(v0) | ((u32)f2bf(v1) << 16);
        }
        u16* dst = xb + ((size_t)(b * N_ + n0 + n)) * 64 + q * 16;
        *(uint4*)dst       = make_uint4(p[0], p[1], p[2], p[3]);
        *(uint4*)(dst + 8) = make_uint4(p[4], p[5], p[6], p[7]);
    }
}

// ---------------------------------------------------------------------------
// fused (round-7): MLP-maximized gather-to-fragment.
//  - ALL 16 gather loads per thread hoisted ahead of the MFMA section:
//    counted vmcnt keeps ~12 loads in flight per wave while node 0
//    computes -> ~4x the outstanding misses of round 5.
//  - W fragments in LDS (16 KB), read per-MFMA via ds_read_b128: frees
//    64 VGPRs so 16 in-flight uint4s fit at >=3 waves/SIMD.
//  - edge prep inline (round-6 showed a separate prep kernel serializes).
// ---------------------------------------------------------------------------
__global__ __launch_bounds__(256, 3)
void fused(const int* __restrict__ ei, const float* __restrict__ pos,
           const u16* __restrict__ xb, const u16* __restrict__ wfrag,
           const float* __restrict__ bias, float* __restrict__ out) {
    __shared__ uint2 esl[256];          // (i0 | i1<<16, s) per edge
    __shared__ u16   wlds[16 * 64 * 8]; // 16 KB: W fragments
    __shared__ float otile[16][66];     // [n_local][o], padded

    const int bi   = blockIdx.x;
    const int b    = bi / NB;
    const int n0   = (bi % NB) * TN;
    const int t    = threadIdx.x;
    const int lane = t & 63;
    const int w    = t >> 6;
    const int g    = lane >> 4;         // k-slice group 0..3
    const int col  = lane & 15;

    // ---- Phase A: edge prep (1 edge/thread) + W-frag global->LDS copy ----
    {
        const int idx = n0 * K_ + t;
        int i0 = ei[(size_t)b * N_ * K_ + idx];          // neighbor (x_j)
        int i1 = ei[((size_t)B_ + b) * N_ * K_ + idx];   // center   (x_i)
        const float* pb = pos + (size_t)b * 3 * N_;
        float dx = pb[i0]          - pb[i1];
        float dy = pb[N_ + i0]     - pb[N_ + i1];
        float dz = pb[2 * N_ + i0] - pb[2 * N_ + i1];
        float dis = sqrtf(dx * dx + dy * dy + dz * dz);
        float s = 2.0f / (1.0f + __expf(dis));           // 2*sigmoid(-dis)
        esl[t] = make_uint2((u32)i0 | ((u32)i1 << 16), __float_as_uint(s));
        #pragma unroll
        for (int r = 0; r < 4; ++r) {
            int e = r * 256 + t;
            ((uint4*)wlds)[e] = ((const uint4*)wfrag)[e];
        }
    }
    const float bo0 = bias[col], bo1 = bias[16 + col],
                bo2 = bias[32 + col], bo3 = bias[48 + col];
    __syncthreads();

    const uint4* xrow = (const uint4*)(xb + (size_t)b * N_ * 64);

    // ---- hoisted gathers: this thread's FULL gather volume (16 uint4) ----
    uint2 eA = esl[(w)      * 16 + col];
    uint2 eB = esl[(4 + w)  * 16 + col];
    uint2 eC = esl[(8 + w)  * 16 + col];
    uint2 eD = esl[(12 + w) * 16 + col];
    const uint4* riA = xrow + ((size_t)(eA.x >> 16) << 3);
    const uint4* rjA = xrow + ((size_t)(eA.x & 0xFFFFu) << 3);
    const uint4* riB = xrow + ((size_t)(eB.x >> 16) << 3);
    const uint4* rjB = xrow + ((size_t)(eB.x & 0xFFFFu) << 3);
    const uint4* riC = xrow + ((size_t)(eC.x >> 16) << 3);
    const uint4* rjC = xrow + ((size_t)(eC.x & 0xFFFFu) << 3);
    const uint4* riD = xrow + ((size_t)(eD.x >> 16) << 3);
    const uint4* rjD = xrow + ((size_t)(eD.x & 0xFFFFu) << 3);

    uint4 A0 = riA[g], A1 = riA[4 + g], A2 = rjA[g], A3 = rjA[4 + g];
    uint4 B0 = riB[g], B1 = riB[4 + g], B2 = rjB[g], B3 = rjB[4 + g];
    uint4 C0 = riC[g], C1 = riC[4 + g], C2 = rjC[g], C3 = rjC[4 + g];
    uint4 D0 = riD[g], D1 = riD[4 + g], D2 = rjD[g], D3 = rjD[4 + g];

#define WF(F) (*(const bf16x8*)&wlds[(size_t)((F) * 64 + lane) * 8])

#define NODE(NT, L0, L1, L2, L3) { \
    f32x4 ac0 = {0,0,0,0}, ac1 = ac0, ac2 = ac0, ac3 = ac0; \
    bf16x8 f0 = asbf(L0), f1 = asbf(L1), f2 = asbf(L2), f3 = asbf(L3); \
    ac0 = __builtin_amdgcn_mfma_f32_16x16x32_bf16(f0, WF(0),  ac0, 0,0,0); \
    ac0 = __builtin_amdgcn_mfma_f32_16x16x32_bf16(f1, WF(1),  ac0, 0,0,0); \
    ac0 = __builtin_amdgcn_mfma_f32_16x16x32_bf16(f2, WF(2),  ac0, 0,0,0); \
    ac0 = __builtin_amdgcn_mfma_f32_16x16x32_bf16(f3, WF(3),  ac0, 0,0,0); \
    ac1 = __builtin_amdgcn_mfma_f32_16x16x32_bf16(f0, WF(4),  ac1, 0,0,0); \
    ac1 = __builtin_amdgcn_mfma_f32_16x16x32_bf16(f1, WF(5),  ac1, 0,0,0); \
    ac1 = __builtin_amdgcn_mfma_f32_16x16x32_bf16(f2, WF(6),  ac1, 0,0,0); \
    ac1 = __builtin_amdgcn_mfma_f32_16x16x32_bf16(f3, WF(7),  ac1, 0,0,0); \
    ac2 = __builtin_amdgcn_mfma_f32_16x16x32_bf16(f0, WF(8),  ac2, 0,0,0); \
    ac2 = __builtin_amdgcn_mfma_f32_16x16x32_bf16(f1, WF(9),  ac2, 0,0,0); \
    ac2 = __builtin_amdgcn_mfma_f32_16x16x32_bf16(f2, WF(10), ac2, 0,0,0); \
    ac2 = __builtin_amdgcn_mfma_f32_16x16x32_bf16(f3, WF(11), ac2, 0,0,0); \
    ac3 = __builtin_amdgcn_mfma_f32_16x16x32_bf16(f0, WF(12), ac3, 0,0,0); \
    ac3 = __builtin_amdgcn_mfma_f32_16x16x32_bf16(f1, WF(13), ac3, 0,0,0); \
    ac3 = __builtin_amdgcn_mfma_f32_16x16x32_bf16(f2, WF(14), ac3, 0,0,0); \
    ac3 = __builtin_amdgcn_mfma_f32_16x16x32_bf16(f3, WF(15), ac3, 0,0,0); \
    float m0 = 0.f, m1 = 0.f, m2 = 0.f, m3 = 0.f; \
    _Pragma("unroll") \
    for (int r4 = 0; r4 < 4; ++r4) { \
        float sv = uasf(esl[(NT) * 16 + g * 4 + r4].y); \
        m0 = fmaxf(m0, fmaxf(ac0[r4] + bo0, 0.f) * sv); \
        m1 = fmaxf(m1, fmaxf(ac1[r4] + bo1, 0.f) * sv); \
        m2 = fmaxf(m2, fmaxf(ac2[r4] + bo2, 0.f) * sv); \
        m3 = fmaxf(m3, fmaxf(ac3[r4] + bo3, 0.f) * sv); \
    } \
    m0 = fmaxf(m0, __shfl_xor(m0, 16)); m0 = fmaxf(m0, __shfl_xor(m0, 32)); \
    m1 = fmaxf(m1, __shfl_xor(m1, 16)); m1 = fmaxf(m1, __shfl_xor(m1, 32)); \
    m2 = fmaxf(m2, __shfl_xor(m2, 16)); m2 = fmaxf(m2, __shfl_xor(m2, 32)); \
    m3 = fmaxf(m3, __shfl_xor(m3, 16)); m3 = fmaxf(m3, __shfl_xor(m3, 32)); \
    if (lane < 16) { \
        otile[NT][col]      = m0; \
        otile[NT][16 + col] = m1; \
        otile[NT][32 + col] = m2; \
        otile[NT][48 + col] = m3; \
    } }

    NODE(w,      A0, A1, A2, A3)
    NODE(4 + w,  B0, B1, B2, B3)
    NODE(8 + w,  C0, C1, C2, C3)
    NODE(12 + w, D0, D1, D2, D3)
#undef NODE
#undef WF
    __syncthreads();

    // ---- coalesced writeback: 64 o x 16 n, nontemporal ----
    #pragma unroll
    for (int r = 0; r < 4; ++r) {
        int flat = r * 256 + t;
        int o = flat >> 4, n2 = flat & 15;
        __builtin_nontemporal_store(otile[n2][o],
            &out[((size_t)b * COUT_ + o) * N_ + n0 + n2]);
    }
}

// ---------------------------------------------------------------------------
extern "C" void kernel_launch(void* const* d_in, const int* in_sizes, int n_in,
                              void* d_out, int out_size, void* d_ws, size_t ws_size,
                              hipStream_t stream) {
    const float* x    = (const float*)d_in[0];   // [B, C, N, 1]
    const int*   ei   = (const int*)  d_in[1];   // [2, B, N, K]
    const float* pos  = (const float*)d_in[2];   // [B, 3, N, 1]
    const float* W    = (const float*)d_in[3];   // [COUT, 2C]
    const float* bias = (const float*)d_in[4];   // [COUT]
    float*       out  = (float*)d_out;           // [B, COUT, N, 1]

    u16* xb    = (u16*)d_ws;                     // B*N*64 bf16 = 5.12 MB
    u16* wfrag = xb + (size_t)B_ * N_ * 64;      // 16 KB (B-frag layout)

    hipLaunchKernelGGL(precast, dim3(B_ * NBC + 1), dim3(256), 0, stream,
                       x, W, xb, wfrag);
    hipLaunchKernelGGL(fused, dim3(B_ * NB), dim3(256), 0, stream,
                       ei, pos, xb, wfrag, bias, out);
}